// Round 1
// baseline (330.090 us; speedup 1.0000x reference)
//
#include <hip/hip_runtime.h>
#include <stdint.h>

typedef __attribute__((ext_vector_type(8))) short bf16x8;
typedef __attribute__((ext_vector_type(4))) float f32x4;

#define HH   100   // history length
#define DD   128   // embedding dim d
#define HID  256   // hidden (= number of W1 rows)
#define MROWS 128  // padded row count for MFMA (100 -> 128)
#define ROWP 264   // LDS X row pitch in ushorts (256 + 8 pad, keeps 16B align, breaks bank aliasing)

__device__ __forceinline__ unsigned short f2bf(float f) {
    unsigned int u = __float_as_uint(f);
    u += 0x7fffu + ((u >> 16) & 1u);   // round-to-nearest-even
    return (unsigned short)(u >> 16);
}

// Convert W1 (256x256 fp32) -> bf16 in workspace. 64 blocks x 256 thr x 4 elems.
__global__ void w1_to_bf16(const float* __restrict__ W1, unsigned short* __restrict__ W1bf) {
    int i = (blockIdx.x * 256 + threadIdx.x) * 4;
    float4 v = *(const float4*)(W1 + i);
    ushort4 o;
    o.x = f2bf(v.x); o.y = f2bf(v.y); o.z = f2bf(v.z); o.w = f2bf(v.w);
    *(ushort4*)(W1bf + i) = o;
}

__global__ __launch_bounds__(256, 2) void nais_kernel(
    const int* __restrict__ history,          // [B,HH]
    const int* __restrict__ target,           // [B]
    const int* __restrict__ history_region,   // [B,HH]
    const int* __restrict__ target_region,    // [B]
    const float* __restrict__ target_distance,// [B]
    const float* __restrict__ E_hist,         // [item,128]
    const float* __restrict__ E_tgt,          // [item,128]
    const float* __restrict__ E_reg,          // [region,128]
    const float* __restrict__ E_dist,         // [16,128]
    const float* __restrict__ b1,             // [256]
    const float* __restrict__ w2,             // [256]
    const unsigned short* __restrict__ W1bf,  // [256][256] bf16
    float* __restrict__ out)                  // [B]
{
    __shared__ unsigned short Xs[MROWS * ROWP];  // 67584 B
    __shared__ float score[MROWS];
    __shared__ float xsum[MROWS];
    __shared__ float eA[MROWS];
    __shared__ float exs[MROWS];
    __shared__ int hidx[HH];
    __shared__ int hreg[HH];
    __shared__ float s_sumE;

    const int b    = blockIdx.x;
    const int t    = threadIdx.x;
    const int lane = t & 63;
    const int wave = t >> 6;

    const int   tg    = target[b];
    const int   trg   = target_region[b];
    const float tdist = target_distance[b];

    // ---- phase 0: stage indices, zero accumulators, pad rows, sum(E_dist[0]) ----
    if (t < HH) {
        hidx[t] = history[b * HH + t];
        hreg[t] = history_region[b * HH + t];
    }
    if (t < MROWS) score[t] = 0.f;
    for (int i = t; i < (MROWS - HH) * ROWP; i += 256)
        Xs[HH * ROWP + i] = 0;   // zero pad rows 100..127 (avoid NaN garbage in MFMA)
    if (wave == 1) {
        float v = E_dist[lane] + E_dist[64 + lane];
        #pragma unroll
        for (int off = 32; off; off >>= 1) v += __shfl_xor(v, off);
        if (lane == 0) s_sumE = v;
    }

    // target vector fragment (per-lane float4 over the concat dim)
    float4 tgt4;
    if (lane < 32) tgt4 = *(const float4*)(E_tgt + (size_t)tg * DD + lane * 4);
    else           tgt4 = *(const float4*)(E_reg + (size_t)trg * DD + (lane - 32) * 4);

    __syncthreads();

    // ---- phase 1: build X[h,:] = hist .* tgt (bf16 in LDS) + xsum[h] ----
    // wave w handles h = h0 + w; 64 lanes cover the 256-dim concat row as float4
    #pragma unroll
    for (int h0 = 0; h0 < HH; h0 += 4) {
        const int h  = h0 + wave;
        const int ih = hidx[h];
        const int ir = hreg[h];
        float4 v;
        if (lane < 32) v = *(const float4*)(E_hist + (size_t)ih * DD + lane * 4);
        else           v = *(const float4*)(E_reg + (size_t)ir * DD + (lane - 32) * 4);
        float x0 = v.x * tgt4.x, x1 = v.y * tgt4.y, x2 = v.z * tgt4.z, x3 = v.w * tgt4.w;
        float s = x0 + x1 + x2 + x3;
        #pragma unroll
        for (int off = 32; off; off >>= 1) s += __shfl_xor(s, off);
        if (lane == 0) xsum[h] = s;
        ushort4 xb;
        xb.x = f2bf(x0); xb.y = f2bf(x1); xb.z = f2bf(x2); xb.w = f2bf(x3);
        *(ushort4*)(Xs + h * ROWP + lane * 4) = xb;
    }

    __syncthreads();

    // ---- phase 2: z = X @ W1^T via MFMA, fused relu/b1/w2 epilogue -> score ----
    // 2x2 wave decomposition: wm picks 64-row half, wn picks 128-col half.
    const int wm    = wave & 1;
    const int wn    = wave >> 1;
    const int mbase = wm * 64;
    const int col   = lane & 15;
    const int quad  = lane >> 4;

    // A fragments: held in registers for the whole n-loop (4 m-tiles x 8 k-steps)
    bf16x8 afrag[4][8];
    #pragma unroll
    for (int mt = 0; mt < 4; mt++) {
        const unsigned short* ap = Xs + (mbase + mt * 16 + col) * ROWP + quad * 8;
        #pragma unroll
        for (int s = 0; s < 8; s++)
            afrag[mt][s] = *(const bf16x8*)(ap + s * 32);
    }

    float sacc[4][4] = {};
    #pragma unroll
    for (int st = 0; st < 8; st++) {
        const int n0 = wn * 128 + st * 16;
        const unsigned short* bp = W1bf + (size_t)(n0 + col) * HID + quad * 8;
        f32x4 acc[4];
        #pragma unroll
        for (int mt = 0; mt < 4; mt++) acc[mt] = (f32x4){0.f, 0.f, 0.f, 0.f};
        #pragma unroll
        for (int s = 0; s < 8; s++) {
            bf16x8 bfrag = *(const bf16x8*)(bp + s * 32);   // L2-resident W1
            #pragma unroll
            for (int mt = 0; mt < 4; mt++)
                acc[mt] = __builtin_amdgcn_mfma_f32_16x16x32_bf16(afrag[mt][s], bfrag, acc[mt], 0, 0, 0);
        }
        // epilogue: z -> relu(z+b1)*w2, reduce over the 16 cols of this strip
        const float bb = b1[n0 + col];
        const float ww = w2[n0 + col];
        #pragma unroll
        for (int mt = 0; mt < 4; mt++) {
            #pragma unroll
            for (int r = 0; r < 4; r++) {
                float z = acc[mt][r] + bb;
                z = (z > 0.f) ? z * ww : 0.f;
                z += __shfl_xor(z, 1);
                z += __shfl_xor(z, 2);
                z += __shfl_xor(z, 4);
                z += __shfl_xor(z, 8);
                sacc[mt][r] += z;
            }
        }
    }
    if (col == 0) {
        #pragma unroll
        for (int mt = 0; mt < 4; mt++) {
            #pragma unroll
            for (int r = 0; r < 4; r++)
                atomicAdd(&score[mbase + mt * 16 + quad * 4 + r], sacc[mt][r]);
        }
    }

    __syncthreads();

    // ---- phase 3: masked exp, beta-power denom, weighted sum, sigmoid ----
    const float dist = tdist * s_sumE;
    if (t < HH) {
        float e = (hidx[t] != tg) ? expf(score[t] + dist) : 0.f;
        eA[t]  = e;
        exs[t] = e * xsum[t];
    }
    __syncthreads();
    if (t < 64) {
        float s1 = eA[t]  + ((t + 64 < HH) ? eA[t + 64]  : 0.f);
        float s2 = exs[t] + ((t + 64 < HH) ? exs[t + 64] : 0.f);
        #pragma unroll
        for (int off = 32; off; off >>= 1) {
            s1 += __shfl_xor(s1, off);
            s2 += __shfl_xor(s2, off);
        }
        if (t == 0) {
            float pred = s2 / sqrtf(s1);   // exp_sum^0.5 (BETA=0.5)
            out[b] = 1.f / (1.f + expf(-pred));
        }
    }
}

extern "C" void kernel_launch(void* const* d_in, const int* in_sizes, int n_in,
                              void* d_out, int out_size, void* d_ws, size_t ws_size,
                              hipStream_t stream) {
    const int*   history         = (const int*)d_in[0];
    const int*   target          = (const int*)d_in[1];
    const int*   history_region  = (const int*)d_in[2];
    const int*   target_region   = (const int*)d_in[3];
    const float* target_distance = (const float*)d_in[4];
    const float* E_hist          = (const float*)d_in[5];
    const float* E_tgt           = (const float*)d_in[6];
    const float* E_reg           = (const float*)d_in[7];
    const float* E_dist          = (const float*)d_in[8];
    const float* W1              = (const float*)d_in[9];
    const float* b1              = (const float*)d_in[10];
    const float* w2              = (const float*)d_in[11];

    unsigned short* W1bf = (unsigned short*)d_ws;  // 131072 B needed
    const int B = in_sizes[1];

    w1_to_bf16<<<64, 256, 0, stream>>>(W1, W1bf);
    nais_kernel<<<B, 256, 0, stream>>>(history, target, history_region, target_region,
                                       target_distance, E_hist, E_tgt, E_reg, E_dist,
                                       b1, w2, W1bf, (float*)d_out);
}

// Round 2
// 238.676 us; speedup vs baseline: 1.3830x; 1.3830x over previous
//
#include <hip/hip_runtime.h>
#include <stdint.h>

typedef __attribute__((ext_vector_type(8))) short bf16x8;
typedef __attribute__((ext_vector_type(4))) float f32x4;

#define HH  100   // history length
#define DD  128   // embedding dim d
#define HID 256   // hidden width / concat dim

__device__ __forceinline__ unsigned short f2bf(float f) {
    unsigned int u = __float_as_uint(f);
    u += 0x7fffu + ((u >> 16) & 1u);   // round-to-nearest-even
    return (unsigned short)(u >> 16);
}

// Pack W1 (256x256 f32, [n][k]) into MFMA B-fragment order, bf16.
// unit = (st*8+s)*64 + lane holds W1[st*16 + (lane&15)][s*32 + (lane>>4)*8 + j], j=0..7
// Phase-2 B loads then read 1 KB fully-contiguous per wave instruction.
__global__ void w1_pack(const float* __restrict__ W1, unsigned short* __restrict__ W1p) {
    int unit = blockIdx.x * 256 + threadIdx.x;   // 0..8191
    int lane = unit & 63;
    int s    = (unit >> 6) & 7;
    int st   = unit >> 9;
    int col  = lane & 15, quad = lane >> 4;
    const float* src = W1 + (size_t)(st * 16 + col) * HID + s * 32 + quad * 8;
    union { unsigned short u[8]; bf16x8 v; } o;
    #pragma unroll
    for (int j = 0; j < 8; j++) o.u[j] = f2bf(src[j]);
    *(bf16x8*)(W1p + (size_t)unit * 8) = o.v;
}

__global__ __launch_bounds__(256, 3) void nais_kernel(
    const int* __restrict__ history,           // [B,HH]
    const int* __restrict__ target,            // [B]
    const int* __restrict__ history_region,    // [B,HH]
    const int* __restrict__ target_region,     // [B]
    const float* __restrict__ target_distance, // [B]
    const float* __restrict__ E_hist,          // [item,128]
    const float* __restrict__ E_tgt,           // [item,128]
    const float* __restrict__ E_reg,           // [region,128]
    const float* __restrict__ E_dist,          // [16,128]
    const float* __restrict__ b1,              // [256]
    const float* __restrict__ w2,              // [256]
    const unsigned short* __restrict__ W1p,    // packed bf16 B-fragments
    float* __restrict__ out)                   // [B]
{
    // X stored swizzled: ushort index = row*256 + ((k>>3) ^ (row&7))*8 + (k&7)
    __shared__ __align__(16) unsigned short Xs[HH * 256];  // 51200 B
    __shared__ float score[128];
    __shared__ float xsum[HH];
    __shared__ float eA[HH];
    __shared__ float exs[HH];
    __shared__ int hidx[HH];
    __shared__ int hreg[HH];
    __shared__ float s_sumE;

    const int b    = blockIdx.x;
    const int t    = threadIdx.x;
    const int lane = t & 63;
    const int wave = t >> 6;

    const int   tg    = target[b];
    const int   trg   = target_region[b];
    const float tdist = target_distance[b];

    // ---- phase 0: stage indices, sum(E_dist[0]) ----
    if (t < HH) {
        hidx[t] = history[b * HH + t];
        hreg[t] = history_region[b * HH + t];
    }
    if (wave == 1) {
        float v = E_dist[lane] + E_dist[64 + lane];
        #pragma unroll
        for (int off = 32; off; off >>= 1) v += __shfl_xor(v, off);
        if (lane == 0) s_sumE = v;
    }

    // target vector fragment (64 lanes cover the 256-float concat row as float4)
    float4 tgt4;
    if (lane < 32) tgt4 = *(const float4*)(E_tgt + (size_t)tg * DD + lane * 4);
    else           tgt4 = *(const float4*)(E_reg + (size_t)trg * DD + (lane - 32) * 4);

    __syncthreads();

    // ---- phase 1: X[h,:] = hist .* tgt (bf16, swizzled into LDS) + xsum[h] ----
    for (int h0 = 0; h0 < HH; h0 += 4) {
        const int h  = h0 + wave;
        const int ih = hidx[h];
        const int ir = hreg[h];
        float4 v;
        if (lane < 32) v = *(const float4*)(E_hist + (size_t)ih * DD + lane * 4);
        else           v = *(const float4*)(E_reg + (size_t)ir * DD + (lane - 32) * 4);
        float x0 = v.x * tgt4.x, x1 = v.y * tgt4.y, x2 = v.z * tgt4.z, x3 = v.w * tgt4.w;
        float s = x0 + x1 + x2 + x3;
        #pragma unroll
        for (int off = 32; off; off >>= 1) s += __shfl_xor(s, off);
        if (lane == 0) xsum[h] = s;
        ushort4 xb;
        xb.x = f2bf(x0); xb.y = f2bf(x1); xb.z = f2bf(x2); xb.w = f2bf(x3);
        // k = lane*4 ; unit u = lane>>1 ; swizzled su = u ^ (h&7) ; in-unit ofs = (lane&1)*4
        const int su = (lane >> 1) ^ (h & 7);
        *(ushort4*)(Xs + h * 256 + su * 8 + (lane & 1) * 4) = xb;
    }

    __syncthreads();

    // ---- phase 2: score = relu(X @ W1^T + b1) . w2 via MFMA ----
    // 1x4 wave split: wave w owns m-tiles {2w, 2w+1} (rows 32w..32w+31), all 256 cols.
    const int col   = lane & 15;
    const int quad  = lane >> 4;
    const int tile0 = wave * 2;

    // A fragments in registers (64 VGPRs) — rows >= 100 are zero (predicated load)
    bf16x8 afrag[2][8];
    #pragma unroll
    for (int mt = 0; mt < 2; mt++) {
        const int row = (tile0 + mt) * 16 + col;
        #pragma unroll
        for (int s = 0; s < 8; s++) {
            bf16x8 f = {0, 0, 0, 0, 0, 0, 0, 0};
            if (row < HH) {
                const int su = (s * 4 + quad) ^ (col & 7);
                f = *(const bf16x8*)(Xs + row * 256 + su * 8);
            }
            afrag[mt][s] = f;
        }
    }

    float sacc[2][4] = {};
    const bf16x8* bp = (const bf16x8*)W1p + lane;
    #pragma unroll 4
    for (int st = 0; st < 16; st++) {
        const float bb = b1[st * 16 + col];
        const float ww = w2[st * 16 + col];
        f32x4 acc0 = {0.f, 0.f, 0.f, 0.f};
        f32x4 acc1 = {0.f, 0.f, 0.f, 0.f};
        #pragma unroll
        for (int s = 0; s < 8; s++) {
            bf16x8 bfrag = bp[(st * 8 + s) * 64];
            acc0 = __builtin_amdgcn_mfma_f32_16x16x32_bf16(afrag[0][s], bfrag, acc0, 0, 0, 0);
            acc1 = __builtin_amdgcn_mfma_f32_16x16x32_bf16(afrag[1][s], bfrag, acc1, 0, 0, 0);
        }
        // relu(z+b1)*w2, accumulate per-lane (column reduction deferred)
        #pragma unroll
        for (int r = 0; r < 4; r++) {
            float z0 = acc0[r] + bb; sacc[0][r] += (z0 > 0.f) ? z0 * ww : 0.f;
            float z1 = acc1[r] + bb; sacc[1][r] += (z1 > 0.f) ? z1 * ww : 0.f;
        }
    }
    // single column reduction over the 16 cols (lane bits 0..3)
    #pragma unroll
    for (int mt = 0; mt < 2; mt++) {
        #pragma unroll
        for (int r = 0; r < 4; r++) {
            float z = sacc[mt][r];
            z += __shfl_xor(z, 1);
            z += __shfl_xor(z, 2);
            z += __shfl_xor(z, 4);
            z += __shfl_xor(z, 8);
            sacc[mt][r] = z;
        }
    }
    if (col == 0) {
        #pragma unroll
        for (int mt = 0; mt < 2; mt++)
            #pragma unroll
            for (int r = 0; r < 4; r++)
                score[(tile0 + mt) * 16 + quad * 4 + r] = sacc[mt][r];
    }

    __syncthreads();

    // ---- phase 3: masked exp, denom^BETA, weighted sum, sigmoid ----
    const float dist = tdist * s_sumE;
    if (t < HH) {
        float e = (hidx[t] != tg) ? expf(score[t] + dist) : 0.f;
        eA[t]  = e;
        exs[t] = e * xsum[t];
    }
    __syncthreads();
    if (t < 64) {
        float s1 = eA[t]  + ((t + 64 < HH) ? eA[t + 64]  : 0.f);
        float s2 = exs[t] + ((t + 64 < HH) ? exs[t + 64] : 0.f);
        #pragma unroll
        for (int off = 32; off; off >>= 1) {
            s1 += __shfl_xor(s1, off);
            s2 += __shfl_xor(s2, off);
        }
        if (t == 0) {
            float pred = s2 / sqrtf(s1);   // exp_sum^0.5 (BETA=0.5)
            out[b] = 1.f / (1.f + expf(-pred));
        }
    }
}

extern "C" void kernel_launch(void* const* d_in, const int* in_sizes, int n_in,
                              void* d_out, int out_size, void* d_ws, size_t ws_size,
                              hipStream_t stream) {
    const int*   history         = (const int*)d_in[0];
    const int*   target          = (const int*)d_in[1];
    const int*   history_region  = (const int*)d_in[2];
    const int*   target_region   = (const int*)d_in[3];
    const float* target_distance = (const float*)d_in[4];
    const float* E_hist          = (const float*)d_in[5];
    const float* E_tgt           = (const float*)d_in[6];
    const float* E_reg           = (const float*)d_in[7];
    const float* E_dist          = (const float*)d_in[8];
    const float* W1              = (const float*)d_in[9];
    const float* b1              = (const float*)d_in[10];
    const float* w2              = (const float*)d_in[11];

    unsigned short* W1p = (unsigned short*)d_ws;  // 131072 B
    const int B = in_sizes[1];

    w1_pack<<<32, 256, 0, stream>>>(W1, W1p);
    nais_kernel<<<B, 256, 0, stream>>>(history, target, history_region, target_region,
                                       target_distance, E_hist, E_tgt, E_reg, E_dist,
                                       b1, w2, W1p, (float*)d_out);
}